// Round 10
// baseline (483.892 us; speedup 1.0000x reference)
//
#include <hip/hip_runtime.h>

#define CELLS 81
#define ND 9
#define HID 100
#define NP 52    // padded unit-pairs: 50 real + 2 zero
#define PPW 13   // pairs per wave (4 waves x 13 = 52)

typedef float v2f __attribute__((ext_vector_type(2)));

#define W1P_SZ (9 * NP * 8)   // 3744 floats: [d][pair]{A0,A1,B0,B1,C0,C1,0,0}
#define W2P_SZ (NP * 20)      // 1040 floats: [pair]{d0u0,d0u1,...,d8u0,d8u1,0,0}

__global__ __launch_bounds__(64) void prep_kernel(
    const float* __restrict__ W1, const float* __restrict__ W2,
    float* __restrict__ ws)
{
    const int t = threadIdx.x;
    for (int i = t; i < 9 * NP; i += 64) {
        int d = i / NP, j = i - d * NP;
        float* r = ws + (size_t)i * 8;
        if (j < 50) {
            int u0 = 2 * j, u1 = u0 + 1;
            r[0] = W1[u0*27 + d];      r[1] = W1[u1*27 + d];
            r[2] = W1[u0*27 + 9 + d];  r[3] = W1[u1*27 + 9 + d];
            r[4] = W1[u0*27 + 18 + d]; r[5] = W1[u1*27 + 18 + d];
        } else {
            r[0]=r[1]=r[2]=r[3]=r[4]=r[5]=0.f;
        }
        r[6] = 0.f; r[7] = 0.f;
    }
    for (int j = t; j < NP; j += 64) {
        float* r = ws + W1P_SZ + (size_t)j * 20;
        if (j < 50) {
            int u0 = 2 * j, u1 = u0 + 1;
            #pragma unroll
            for (int d = 0; d < ND; ++d) {
                r[2*d]     = W2[d*HID + u0];
                r[2*d + 1] = W2[d*HID + u1];
            }
        } else {
            #pragma unroll
            for (int d = 0; d < ND; ++d) { r[2*d] = 0.f; r[2*d+1] = 0.f; }
        }
        r[18] = 0.f; r[19] = 0.f;
    }
}

__global__ __launch_bounds__(512, 4) void sudoku_kernel(
    const float* __restrict__ x_all,
    const float* __restrict__ ws,
    float* __restrict__ out,
    int nBoards)
{
    const int tid = threadIdx.x;      // 512 threads: 2 boards x 4 waves
    const int bi  = tid >> 8;         // board within block
    const int bt  = tid & 255;        // thread within board
    const int wv  = bt >> 6;          // wave within board (owns pairs [wv*13, wv*13+13))
    const int lw  = tid & 63;         // lane = empty-cell slot (rank order = q order)
    const int jbase = wv * PPW;

    const int board = blockIdx.x * 2 + bi;
    const bool bvalid = board < nBoards;
    const int bs = bvalid ? board : blockIdx.x * 2;   // safe read index
    const float* x = x_all + (size_t)bs * (CELLS * ND);
    float* po = out + (size_t)bs * (CELLS * ND);
    float* fo = out + (size_t)nBoards * (CELLS * ND) + (size_t)bs * (CELLS * ND);

    __shared__ __align__(16) float w1s[W1P_SZ];           // 14976 B (shared by both boards)
    __shared__ __align__(16) float w2s[W2P_SZ];           // 4160 B
    __shared__ __align__(16) float parts[2][2][4][64][12];// 49152 B dbuf partials
    __shared__ float cnt[2][3 * 81];                      // 1944 B
    __shared__ int   digit[2][CELLS];                     // 648 B
    __shared__ unsigned long long em_sh[2][2];
    __shared__ int   neS[2];

    // ---- stage packed weights (whole block), init per-board state ----
    for (int i = tid; i < W1P_SZ / 4; i += 512)
        ((float4*)w1s)[i] = ((const float4*)ws)[i];
    for (int i = tid; i < W2P_SZ / 4; i += 512)
        ((float4*)w2s)[i] = ((const float4*)(ws + W1P_SZ))[i];
    for (int i = bt; i < 243; i += 256) cnt[bi][i] = 0.f;
    if (bvalid)
        for (int i = bt; i < CELLS * ND; i += 256) po[i] = x[i];
    __syncthreads();

    // ---- digits, counts, per-wave emptiness ballots (waves 0,1 cover 81 cells) ----
    bool isEmpty = false;
    if (bt < CELLS) {
        int q = bt, dig = -1;
        #pragma unroll
        for (int d = 0; d < ND; ++d) if (dig < 0 && x[q*ND+d] > 0.5f) dig = d;
        digit[bi][q] = dig;
        if (dig >= 0) {
            int r = q/9, c = q%9, b = (r/3)*3 + c/3;
            atomicAdd(&cnt[bi][r*9+dig], 1.f);
            atomicAdd(&cnt[bi][81+c*9+dig], 1.f);
            atomicAdd(&cnt[bi][162+b*9+dig], 1.f);
        } else isEmpty = true;
    }
    if (wv < 2) {
        unsigned long long mk = __ballot(isEmpty);   // whole-wave ballot
        if (lw == 0) em_sh[bi][wv] = mk;
    }
    __syncthreads();

    const unsigned long long em0 = em_sh[bi][0], em1 = em_sh[bi][1];
    const int c0 = __popcll(em0);
    int ne0 = c0 + __popcll(em1);
    if (ne0 > 64) ne0 = 64;          // cannot happen at EMPTY_P=0.3, defensive
    if (bt == 0) neS[bi] = ne0;

    // lane lw -> rank-lw empty cell (ascending q; sentinel 127); same in all 4 waves
    int myq = 127;
    if (lw < ne0) {
        int rank = lw; unsigned long long mm = em0; int base = 0;
        if (rank >= c0) { rank -= c0; mm = em1; base = 64; }
        for (int b = 0; b < 64; ++b)
            if ((mm >> b) & 1ull) { if (rank == 0) { myq = base + b; break; } --rank; }
    }
    const int myr = (myq < 81) ? myq / 9 : 0;
    const int myc = (myq < 81) ? myq % 9 : 0;
    const int myb = (myr / 3) * 3 + myc / 3;

    // ---- z init: 27 counts in regs; own 13 pairs from packed W1 ----
    float crr[9], ccc[9], cbb[9];
    #pragma unroll
    for (int j = 0; j < 9; ++j) {
        crr[j] = cnt[bi][myr*9+j];
        ccc[j] = cnt[bi][81+myc*9+j];
        cbb[j] = cnt[bi][162+myb*9+j];
    }
    v2f z2[PPW];
    #pragma unroll
    for (int j = 0; j < PPW; ++j) {
        v2f a = (v2f){0.f, 0.f};
        #pragma unroll
        for (int d = 0; d < 9; ++d) {
            const float* p = &w1s[(d*NP + jbase + j) * 8];
            float4 ab = *(const float4*)p;
            v2f Cv = *(const v2f*)(p + 4);
            v2f Av = (v2f){ab.x, ab.y}, Bv = (v2f){ab.z, ab.w};
            a += crr[d]*Av + ccc[d]*Bv + cbb[d]*Cv;
        }
        z2[j] = a;
    }
    __syncthreads();
    const int itMax = max(neS[0], neS[1]);

    bool active = (lw < ne0);
    v2f b0v = (v2f){0.f,0.f}, b1v = (v2f){0.f,0.f}, b2v = (v2f){0.f,0.f};
    int dc = 0;
    float pfin[ND];

    // ---- solve loop: 1 barrier/iter; both boards lockstep to itMax ----
    for (int it = 0; it < itMax; ++it) {
        const int dcs = __builtin_amdgcn_readfirstlane(dc);
        const float* w1r = &w1s[(dcs*NP + jbase) * 8];
        const float* w2r = &w2s[jbase * 20];

        v2f acc2[ND];
        #pragma unroll
        for (int d = 0; d < ND; ++d) acc2[d] = (v2f){0.f, 0.f};

        // fused z-update + relu + packed partial logits over own 13 pairs
        #pragma unroll
        for (int j = 0; j < PPW; ++j) {
            const float* p = w1r + j*8;
            float4 ab = *(const float4*)p;
            v2f Cv = *(const v2f*)(p + 4);
            v2f Av = (v2f){ab.x, ab.y}, Bv = (v2f){ab.z, ab.w};
            v2f zv = z2[j];
            zv = b0v*Av + (b1v*Bv + (b2v*Cv + zv));
            z2[j] = zv;
            v2f h;
            h.x = fmaxf(zv.x, 0.f);
            h.y = fmaxf(zv.y, 0.f);
            const float* qq = w2r + j*20;
            float4 w01 = *(const float4*)qq;
            float4 w23 = *(const float4*)(qq + 4);
            float4 w45 = *(const float4*)(qq + 8);
            float4 w67 = *(const float4*)(qq + 12);
            v2f w8 = *(const v2f*)(qq + 16);
            acc2[0] += h * (v2f){w01.x, w01.y};
            acc2[1] += h * (v2f){w01.z, w01.w};
            acc2[2] += h * (v2f){w23.x, w23.y};
            acc2[3] += h * (v2f){w23.z, w23.w};
            acc2[4] += h * (v2f){w45.x, w45.y};
            acc2[5] += h * (v2f){w45.z, w45.w};
            acc2[6] += h * (v2f){w67.x, w67.y};
            acc2[7] += h * (v2f){w67.z, w67.w};
            acc2[8] += h * w8;
        }

        float accp[ND];
        #pragma unroll
        for (int d = 0; d < ND; ++d) accp[d] = acc2[d].x + acc2[d].y;

        // publish partial; combine all 4 in FIXED wave order -> bit-identical
        const int buf = it & 1;
        float* pp = &parts[buf][bi][wv][lw][0];
        *(float4*)(pp)     = make_float4(accp[0], accp[1], accp[2], accp[3]);
        *(float4*)(pp + 4) = make_float4(accp[4], accp[5], accp[6], accp[7]);
        pp[8] = accp[8];
        __syncthreads();

        float acc[ND] = {0.f,0.f,0.f,0.f,0.f,0.f,0.f,0.f,0.f};
        #pragma unroll
        for (int ow = 0; ow < 4; ++ow) {
            const float* op = &parts[buf][bi][ow][lw][0];
            float4 oa = *(const float4*)(op);
            float4 ob = *(const float4*)(op + 4);
            acc[0] += oa.x; acc[1] += oa.y; acc[2] += oa.z; acc[3] += oa.w;
            acc[4] += ob.x; acc[5] += ob.y; acc[6] += ob.z; acc[7] += ob.w;
            acc[8] += op[8];
        }

        // softmax + per-cell best digit (strict >: first max)
        float m9 = fmaxf(fmaxf(fmaxf(acc[0],acc[1]), fmaxf(acc[2],acc[3])),
                         fmaxf(fmaxf(acc[4],acc[5]), fmaxf(acc[6],acc[7])));
        m9 = fmaxf(m9, acc[8]);
        float s = 0.f;
        #pragma unroll
        for (int d = 0; d < ND; ++d) { acc[d] = __expf(acc[d] - m9); s += acc[d]; }
        float inv = 1.f / s;
        float bv = -1.f; int bd = 0;
        #pragma unroll
        for (int d = 0; d < ND; ++d) {
            acc[d] *= inv;
            if (acc[d] > bv) { bv = acc[d]; bd = d; }
        }

        // winner: max butterfly + ballot (lowest lane = lowest q = first occurrence)
        float bvv = active ? bv : -1.f;
        float vmax = bvv;
        #pragma unroll
        for (int off = 32; off >= 1; off >>= 1)
            vmax = fmaxf(vmax, __shfl_xor(vmax, off));
        unsigned long long msk = __ballot(bvv == vmax);
        int wl = __ffsll(msk) - 1;
        int qw = __shfl(myq, wl);
        int dw = __shfl(bd, wl);

        if (active && myq == qw) {
            #pragma unroll
            for (int d = 0; d < ND; ++d) pfin[d] = acc[d];
            if (wv == 0) digit[bi][myq] = dw;
            active = false;
        }
        const int pr = qw/9, pcc = qw%9, pb = (pr/3)*3 + pcc/3;
        b0v = (v2f)((myr == pr)  ? 1.f : 0.f);
        b1v = (v2f)((myc == pcc) ? 1.f : 0.f);
        b2v = (v2f)((myb == pb)  ? 1.f : 0.f);
        dc = dw;
    }

    // ---- outputs ----
    __syncthreads();
    if (bvalid && wv == 0 && lw < ne0 && myq < 81) {
        #pragma unroll
        for (int d = 0; d < ND; ++d) po[myq*ND + d] = pfin[d];
    }
    if (bvalid) {
        for (int i = bt; i < CELLS * ND; i += 256) {
            int q = i / ND, d = i - q * ND;
            fo[i] = (digit[bi][q] == d) ? 1.f : 0.f;
        }
    }
}

extern "C" void kernel_launch(void* const* d_in, const int* in_sizes, int n_in,
                              void* d_out, int out_size, void* d_ws, size_t ws_size,
                              hipStream_t stream) {
    const float* x  = (const float*)d_in[0];
    // d_in[1] is the constraint mask c — structurally known, not needed.
    const float* W1 = (const float*)d_in[2];
    const float* W2 = (const float*)d_in[3];
    float* out = (float*)d_out;
    float* ws  = (float*)d_ws;
    int nBoards = in_sizes[0] / (CELLS * ND);
    prep_kernel<<<1, 64, 0, stream>>>(W1, W2, ws);
    int nBlk = (nBoards + 1) / 2;
    sudoku_kernel<<<nBlk, 512, 0, stream>>>(x, ws, out, nBoards);
}

// Round 11
// 449.093 us; speedup vs baseline: 1.0775x; 1.0775x over previous
//
#include <hip/hip_runtime.h>

#define CELLS 81
#define ND 9
#define HID 100
#define NP 52    // padded unit-pairs: 50 real + 2 zero
#define PPW 13   // pairs per wave (4 waves x 13 = 52)

typedef float v2f __attribute__((ext_vector_type(2)));

#define W1P_SZ (9 * NP * 8)   // 3744 floats: [d][pair]{A0,A1,B0,B1,C0,C1,0,0}
#define W2P_SZ (NP * 20)      // 1040 floats: [pair]{d0u0,d0u1,...,d8u0,d8u1,0,0}

__global__ __launch_bounds__(64) void prep_kernel(
    const float* __restrict__ W1, const float* __restrict__ W2,
    float* __restrict__ ws)
{
    const int t = threadIdx.x;
    for (int i = t; i < 9 * NP; i += 64) {
        int d = i / NP, j = i - d * NP;
        float* r = ws + (size_t)i * 8;
        if (j < 50) {
            int u0 = 2 * j, u1 = u0 + 1;
            r[0] = W1[u0*27 + d];      r[1] = W1[u1*27 + d];
            r[2] = W1[u0*27 + 9 + d];  r[3] = W1[u1*27 + 9 + d];
            r[4] = W1[u0*27 + 18 + d]; r[5] = W1[u1*27 + 18 + d];
        } else {
            r[0]=r[1]=r[2]=r[3]=r[4]=r[5]=0.f;
        }
        r[6] = 0.f; r[7] = 0.f;
    }
    for (int j = t; j < NP; j += 64) {
        float* r = ws + W1P_SZ + (size_t)j * 20;
        if (j < 50) {
            int u0 = 2 * j, u1 = u0 + 1;
            #pragma unroll
            for (int d = 0; d < ND; ++d) {
                r[2*d]     = W2[d*HID + u0];
                r[2*d + 1] = W2[d*HID + u1];
            }
        } else {
            #pragma unroll
            for (int d = 0; d < ND; ++d) { r[2*d] = 0.f; r[2*d+1] = 0.f; }
        }
        r[18] = 0.f; r[19] = 0.f;
    }
}

// NOTE: no min-blocks hint! (512,4) caps VGPR at 64 -> spills -> 400MB scratch
// traffic (round-10 post-mortem). LDS (71KB) already pins 2 blocks/CU.
__global__ __launch_bounds__(512) void sudoku_kernel(
    const float* __restrict__ x_all,
    const float* __restrict__ ws,
    float* __restrict__ out,
    int nBoards)
{
    const int tid = threadIdx.x;      // 512 threads: 2 boards x 4 waves
    const int bi  = tid >> 8;         // board within block
    const int bt  = tid & 255;        // thread within board
    const int wv  = bt >> 6;          // wave within board (owns pairs [wv*13, wv*13+13))
    const int lw  = tid & 63;         // lane = empty-cell slot (rank order = q order)
    const int jbase = wv * PPW;

    const int board = blockIdx.x * 2 + bi;
    const bool bvalid = board < nBoards;
    const int bs = bvalid ? board : blockIdx.x * 2;   // safe read index
    const float* x = x_all + (size_t)bs * (CELLS * ND);
    float* po = out + (size_t)bs * (CELLS * ND);
    float* fo = out + (size_t)nBoards * (CELLS * ND) + (size_t)bs * (CELLS * ND);

    __shared__ __align__(16) float w1s[W1P_SZ];           // 14976 B (shared by both boards)
    __shared__ __align__(16) float w2s[W2P_SZ];           // 4160 B
    __shared__ __align__(16) float parts[2][2][4][64][12];// 49152 B dbuf partials
    __shared__ float cnt[2][3 * 81];                      // 1944 B
    __shared__ int   digit[2][CELLS];                     // 648 B
    __shared__ unsigned long long em_sh[2][2];
    __shared__ int   neS[2];

    // ---- stage packed weights (whole block), init per-board state ----
    for (int i = tid; i < W1P_SZ / 4; i += 512)
        ((float4*)w1s)[i] = ((const float4*)ws)[i];
    for (int i = tid; i < W2P_SZ / 4; i += 512)
        ((float4*)w2s)[i] = ((const float4*)(ws + W1P_SZ))[i];
    for (int i = bt; i < 243; i += 256) cnt[bi][i] = 0.f;
    if (bvalid)
        for (int i = bt; i < CELLS * ND; i += 256) po[i] = x[i];
    __syncthreads();

    // ---- digits, counts, per-wave emptiness ballots (waves 0,1 cover 81 cells) ----
    bool isEmpty = false;
    if (bt < CELLS) {
        int q = bt, dig = -1;
        #pragma unroll
        for (int d = 0; d < ND; ++d) if (dig < 0 && x[q*ND+d] > 0.5f) dig = d;
        digit[bi][q] = dig;
        if (dig >= 0) {
            int r = q/9, c = q%9, b = (r/3)*3 + c/3;
            atomicAdd(&cnt[bi][r*9+dig], 1.f);
            atomicAdd(&cnt[bi][81+c*9+dig], 1.f);
            atomicAdd(&cnt[bi][162+b*9+dig], 1.f);
        } else isEmpty = true;
    }
    if (wv < 2) {
        unsigned long long mk = __ballot(isEmpty);   // whole-wave ballot
        if (lw == 0) em_sh[bi][wv] = mk;
    }
    __syncthreads();

    const unsigned long long em0 = em_sh[bi][0], em1 = em_sh[bi][1];
    const int c0 = __popcll(em0);
    int ne0 = c0 + __popcll(em1);
    if (ne0 > 64) ne0 = 64;          // cannot happen at EMPTY_P=0.3, defensive
    if (bt == 0) neS[bi] = ne0;

    // lane lw -> rank-lw empty cell (ascending q; sentinel 127); same in all 4 waves
    int myq = 127;
    if (lw < ne0) {
        int rank = lw; unsigned long long mm = em0; int base = 0;
        if (rank >= c0) { rank -= c0; mm = em1; base = 64; }
        for (int b = 0; b < 64; ++b)
            if ((mm >> b) & 1ull) { if (rank == 0) { myq = base + b; break; } --rank; }
    }
    const int myr = (myq < 81) ? myq / 9 : 0;
    const int myc = (myq < 81) ? myq % 9 : 0;
    const int myb = (myr / 3) * 3 + myc / 3;

    // ---- z init: 27 counts in regs; own 13 pairs from packed W1 ----
    float crr[9], ccc[9], cbb[9];
    #pragma unroll
    for (int j = 0; j < 9; ++j) {
        crr[j] = cnt[bi][myr*9+j];
        ccc[j] = cnt[bi][81+myc*9+j];
        cbb[j] = cnt[bi][162+myb*9+j];
    }
    v2f z2[PPW];
    #pragma unroll
    for (int j = 0; j < PPW; ++j) {
        v2f a = (v2f){0.f, 0.f};
        #pragma unroll
        for (int d = 0; d < 9; ++d) {
            const float* p = &w1s[(d*NP + jbase + j) * 8];
            float4 ab = *(const float4*)p;
            v2f Cv = *(const v2f*)(p + 4);
            v2f Av = (v2f){ab.x, ab.y}, Bv = (v2f){ab.z, ab.w};
            a += crr[d]*Av + ccc[d]*Bv + cbb[d]*Cv;
        }
        z2[j] = a;
    }
    __syncthreads();
    const int itMax = max(neS[0], neS[1]);

    bool active = (lw < ne0);
    v2f b0v = (v2f){0.f,0.f}, b1v = (v2f){0.f,0.f}, b2v = (v2f){0.f,0.f};
    int dc = 0;
    float pfin[ND];

    // ---- solve loop: 1 barrier/iter; both boards lockstep to itMax ----
    for (int it = 0; it < itMax; ++it) {
        const int dcs = __builtin_amdgcn_readfirstlane(dc);
        const float* w1r = &w1s[(dcs*NP + jbase) * 8];
        const float* w2r = &w2s[jbase * 20];

        v2f acc2[ND];
        #pragma unroll
        for (int d = 0; d < ND; ++d) acc2[d] = (v2f){0.f, 0.f};

        // fused z-update + relu + packed partial logits over own 13 pairs
        #pragma unroll
        for (int j = 0; j < PPW; ++j) {
            const float* p = w1r + j*8;
            float4 ab = *(const float4*)p;
            v2f Cv = *(const v2f*)(p + 4);
            v2f Av = (v2f){ab.x, ab.y}, Bv = (v2f){ab.z, ab.w};
            v2f zv = z2[j];
            zv = b0v*Av + (b1v*Bv + (b2v*Cv + zv));
            z2[j] = zv;
            v2f h;
            h.x = fmaxf(zv.x, 0.f);
            h.y = fmaxf(zv.y, 0.f);
            const float* qq = w2r + j*20;
            float4 w01 = *(const float4*)qq;
            float4 w23 = *(const float4*)(qq + 4);
            float4 w45 = *(const float4*)(qq + 8);
            float4 w67 = *(const float4*)(qq + 12);
            v2f w8 = *(const v2f*)(qq + 16);
            acc2[0] += h * (v2f){w01.x, w01.y};
            acc2[1] += h * (v2f){w01.z, w01.w};
            acc2[2] += h * (v2f){w23.x, w23.y};
            acc2[3] += h * (v2f){w23.z, w23.w};
            acc2[4] += h * (v2f){w45.x, w45.y};
            acc2[5] += h * (v2f){w45.z, w45.w};
            acc2[6] += h * (v2f){w67.x, w67.y};
            acc2[7] += h * (v2f){w67.z, w67.w};
            acc2[8] += h * w8;
        }

        float accp[ND];
        #pragma unroll
        for (int d = 0; d < ND; ++d) accp[d] = acc2[d].x + acc2[d].y;

        // publish partial; combine all 4 in FIXED wave order -> bit-identical
        const int buf = it & 1;
        float* pp = &parts[buf][bi][wv][lw][0];
        *(float4*)(pp)     = make_float4(accp[0], accp[1], accp[2], accp[3]);
        *(float4*)(pp + 4) = make_float4(accp[4], accp[5], accp[6], accp[7]);
        pp[8] = accp[8];
        __syncthreads();

        float acc[ND] = {0.f,0.f,0.f,0.f,0.f,0.f,0.f,0.f,0.f};
        #pragma unroll
        for (int ow = 0; ow < 4; ++ow) {
            const float* op = &parts[buf][bi][ow][lw][0];
            float4 oa = *(const float4*)(op);
            float4 ob = *(const float4*)(op + 4);
            acc[0] += oa.x; acc[1] += oa.y; acc[2] += oa.z; acc[3] += oa.w;
            acc[4] += ob.x; acc[5] += ob.y; acc[6] += ob.z; acc[7] += ob.w;
            acc[8] += op[8];
        }

        // softmax + per-cell best digit (strict >: first max)
        float m9 = fmaxf(fmaxf(fmaxf(acc[0],acc[1]), fmaxf(acc[2],acc[3])),
                         fmaxf(fmaxf(acc[4],acc[5]), fmaxf(acc[6],acc[7])));
        m9 = fmaxf(m9, acc[8]);
        float s = 0.f;
        #pragma unroll
        for (int d = 0; d < ND; ++d) { acc[d] = __expf(acc[d] - m9); s += acc[d]; }
        float inv = 1.f / s;
        float bv = -1.f; int bd = 0;
        #pragma unroll
        for (int d = 0; d < ND; ++d) {
            acc[d] *= inv;
            if (acc[d] > bv) { bv = acc[d]; bd = d; }
        }

        // winner: max butterfly + ballot (lowest lane = lowest q = first occurrence)
        float bvv = active ? bv : -1.f;
        float vmax = bvv;
        #pragma unroll
        for (int off = 32; off >= 1; off >>= 1)
            vmax = fmaxf(vmax, __shfl_xor(vmax, off));
        unsigned long long msk = __ballot(bvv == vmax);
        int wl = __ffsll(msk) - 1;
        int qw = __shfl(myq, wl);
        int dw = __shfl(bd, wl);

        if (active && myq == qw) {
            #pragma unroll
            for (int d = 0; d < ND; ++d) pfin[d] = acc[d];
            if (wv == 0) digit[bi][myq] = dw;
            active = false;
        }
        const int pr = qw/9, pcc = qw%9, pb = (pr/3)*3 + pcc/3;
        b0v = (v2f)((myr == pr)  ? 1.f : 0.f);
        b1v = (v2f)((myc == pcc) ? 1.f : 0.f);
        b2v = (v2f)((myb == pb)  ? 1.f : 0.f);
        dc = dw;
    }

    // ---- outputs ----
    __syncthreads();
    if (bvalid && wv == 0 && lw < ne0 && myq < 81) {
        #pragma unroll
        for (int d = 0; d < ND; ++d) po[myq*ND + d] = pfin[d];
    }
    if (bvalid) {
        for (int i = bt; i < CELLS * ND; i += 256) {
            int q = i / ND, d = i - q * ND;
            fo[i] = (digit[bi][q] == d) ? 1.f : 0.f;
        }
    }
}

extern "C" void kernel_launch(void* const* d_in, const int* in_sizes, int n_in,
                              void* d_out, int out_size, void* d_ws, size_t ws_size,
                              hipStream_t stream) {
    const float* x  = (const float*)d_in[0];
    // d_in[1] is the constraint mask c — structurally known, not needed.
    const float* W1 = (const float*)d_in[2];
    const float* W2 = (const float*)d_in[3];
    float* out = (float*)d_out;
    float* ws  = (float*)d_ws;
    int nBoards = in_sizes[0] / (CELLS * ND);
    prep_kernel<<<1, 64, 0, stream>>>(W1, W2, ws);
    int nBlk = (nBoards + 1) / 2;
    sudoku_kernel<<<nBlk, 512, 0, stream>>>(x, ws, out, nBoards);
}

// Round 12
// 139.601 us; speedup vs baseline: 3.4663x; 3.2170x over previous
//
#include <hip/hip_runtime.h>

#define CELLS 81
#define ND 9
#define HID 100
#define NP 52    // padded unit-pairs: 50 real + 2 zero
#define PPW 13   // pairs per wave (4 waves x 13 = 52)

typedef float v2f __attribute__((ext_vector_type(2)));

#define W1P_SZ (9 * NP * 8)      // 3744 floats: [d][pair]{A0,A1,B0,B1,C0,C1,0,0}
#define W2P_SZ (NP * 20)         // 1040 floats: [pair]{d0u0,d0u1,...,d8u0,d8u1,0,0}
#define NE_OFF (W1P_SZ + W2P_SZ) // int word offset of ne[1024]
#define ORD_OFF (NE_OFF + 1024)  // int word offset of order[2048]

__global__ __launch_bounds__(64) void prep_kernel(
    const float* __restrict__ W1, const float* __restrict__ W2,
    float* __restrict__ ws)
{
    const int t = threadIdx.x;
    for (int i = t; i < 9 * NP; i += 64) {
        int d = i / NP, j = i - d * NP;
        float* r = ws + (size_t)i * 8;
        if (j < 50) {
            int u0 = 2 * j, u1 = u0 + 1;
            r[0] = W1[u0*27 + d];      r[1] = W1[u1*27 + d];
            r[2] = W1[u0*27 + 9 + d];  r[3] = W1[u1*27 + 9 + d];
            r[4] = W1[u0*27 + 18 + d]; r[5] = W1[u1*27 + 18 + d];
        } else {
            r[0]=r[1]=r[2]=r[3]=r[4]=r[5]=0.f;
        }
        r[6] = 0.f; r[7] = 0.f;
    }
    for (int j = t; j < NP; j += 64) {
        float* r = ws + W1P_SZ + (size_t)j * 20;
        if (j < 50) {
            int u0 = 2 * j, u1 = u0 + 1;
            #pragma unroll
            for (int d = 0; d < ND; ++d) {
                r[2*d]     = W2[d*HID + u0];
                r[2*d + 1] = W2[d*HID + u1];
            }
        } else {
            #pragma unroll
            for (int d = 0; d < ND; ++d) { r[2*d] = 0.f; r[2*d+1] = 0.f; }
        }
        r[18] = 0.f; r[19] = 0.f;
    }
}

// per-board empty-cell count
__global__ __launch_bounds__(64) void ne_kernel(
    const float* __restrict__ x_all, int* __restrict__ ne, int nBoards)
{
    const int b = blockIdx.x, t = threadIdx.x;
    const float* xb = x_all + (size_t)b * (CELLS * ND);
    float mx = 0.f;
    #pragma unroll
    for (int d = 0; d < ND; ++d) mx = fmaxf(mx, xb[t*ND + d]);
    bool e1 = (mx < 0.5f);
    bool e2 = false;
    if (t < CELLS - 64) {
        float m2 = 0.f;
        #pragma unroll
        for (int d = 0; d < ND; ++d) m2 = fmaxf(m2, xb[(64+t)*ND + d]);
        e2 = (m2 < 0.5f);
    }
    unsigned long long m1 = __ballot(e1), m2b = __ballot(e2);
    if (t == 0) ne[b] = __popcll(m1) + __popcll(m2b);
}

// deterministic partition: smalls (ne<=32) paired in index order; bigs get a
// block to themselves (slot duplicated -> joined 64-lane mode)
__global__ __launch_bounds__(1024) void part_kernel(
    const int* __restrict__ ne, int* __restrict__ order, int nBoards)
{
    __shared__ int sc[1024];
    const int t = threadIdx.x;
    const bool valid = t < nBoards;
    int isS = valid ? ((ne[t] <= 32) ? 1 : 0) : 0;
    sc[t] = isS;
    __syncthreads();
    for (int off = 1; off < 1024; off <<= 1) {
        int v = (t >= off) ? sc[t - off] : 0;
        __syncthreads();
        sc[t] += v;
        __syncthreads();
    }
    const int nSmall = sc[1023];
    const int excl = sc[t] - isS;
    for (int i = t; i < 2048; i += 1024) order[i] = -1;
    __syncthreads();
    const int nPair = (nSmall + 1) >> 1;
    if (valid) {
        if (isS) order[excl] = t;
        else {
            int k = t - excl;               // rank among bigs (invalid ts sort after)
            int base = 2 * nPair + 2 * k;
            order[base] = t; order[base + 1] = t;
        }
    }
    __syncthreads();
    if (t == 0 && (nSmall & 1)) order[nSmall] = order[nSmall - 1];
}

__global__ __launch_bounds__(256, 4) void sudoku_kernel(
    const float* __restrict__ x_all,
    const float* __restrict__ ws,
    const int* __restrict__ order,
    float* __restrict__ out, int nBoards)
{
    const int tid = threadIdx.x;      // 4 waves x 13 pairs
    const int wv  = tid >> 6;
    const int lw  = tid & 63;
    const int h   = lw >> 5;          // 32-lane segment within wave
    const int jbase = wv * PPW;

    const int s0  = order[2 * blockIdx.x];
    const int s1r = order[2 * blockIdx.x + 1];
    if (s0 < 0) return;
    const int s1 = (s1r < 0) ? s0 : s1r;
    const bool joined = (s0 == s1);   // one 64-lane board (big or lone small)
    const int myBoard = h ? s1 : s0;
    const int idx = joined ? 0 : h;   // cnt/digit slot

    float* pom = out + (size_t)myBoard * (CELLS * ND);

    __shared__ __align__(16) float w1s[W1P_SZ];      // 14976 B
    __shared__ __align__(16) float w2s[W2P_SZ];      // 4160 B
    __shared__ float parts[2][4][ND][64];            // 18432 B, conflict-free layout
    __shared__ float cnt[2][3 * 81];                 // 1944 B
    __shared__ int   digit[2][CELLS];                // 648 B

    // ---- stage packed weights, zero counts ----
    for (int i = tid; i < W1P_SZ / 4; i += 256)
        ((float4*)w1s)[i] = ((const float4*)ws)[i];
    for (int i = tid; i < W2P_SZ / 4; i += 256)
        ((float4*)w2s)[i] = ((const float4*)(ws + W1P_SZ))[i];
    for (int i = tid; i < 2 * 243; i += 256) (&cnt[0][0])[i] = 0.f;
    __syncthreads();

    // ---- per-slot digit scan + counts + po init (threads 0-127 slot0, 128-255 slot1) ----
    {
        const int slot = (tid < 128) ? 0 : 1;
        const int t = (tid < 128) ? tid : tid - 128;
        const bool doSlot = (slot == 0) || !joined;
        const int bd = slot ? s1 : s0;
        const float* xb = x_all + (size_t)bd * (CELLS * ND);
        float* pob = out + (size_t)bd * (CELLS * ND);
        if (doSlot) {
            if (t < CELLS) {
                int dig = -1;
                #pragma unroll
                for (int d = 0; d < ND; ++d)
                    if (dig < 0 && xb[t*ND + d] > 0.5f) dig = d;
                digit[slot][t] = dig;
                if (dig >= 0) {
                    int r = t/9, c = t%9, b = (r/3)*3 + c/3;
                    atomicAdd(&cnt[slot][r*9 + dig], 1.f);
                    atomicAdd(&cnt[slot][81 + c*9 + dig], 1.f);
                    atomicAdd(&cnt[slot][162 + b*9 + dig], 1.f);
                }
            }
            for (int i = t; i < CELLS * ND; i += 128) pob[i] = xb[i];
        }
    }
    __syncthreads();

    // ---- rank -> cell via digit scan; ne for both slots ----
    const int rank = joined ? lw : (lw & 31);
    int myq = 127;
    int ne0 = 0, ne1 = 0;
    for (int q = 0; q < CELLS; ++q)
        if (digit[0][q] < 0) { if (idx == 0 && ne0 == rank) myq = q; ++ne0; }
    if (!joined) {
        for (int q = 0; q < CELLS; ++q)
            if (digit[1][q] < 0) { if (idx == 1 && ne1 == rank) myq = q; ++ne1; }
    } else ne1 = ne0;
    const int ne_mine = idx ? ne1 : ne0;
    const int itMax = max(ne0, ne1);
    bool active = (rank < ne_mine);

    const int myr = (myq < 81) ? myq / 9 : 0;
    const int myc = (myq < 81) ? myq % 9 : 0;
    const int myb = (myr / 3) * 3 + myc / 3;

    // ---- z init: 27 counts in regs; own 13 pairs from packed W1 ----
    float crr[9], ccc[9], cbb[9];
    #pragma unroll
    for (int j = 0; j < 9; ++j) {
        crr[j] = cnt[idx][myr*9 + j];
        ccc[j] = cnt[idx][81 + myc*9 + j];
        cbb[j] = cnt[idx][162 + myb*9 + j];
    }
    v2f z2[PPW];
    #pragma unroll
    for (int j = 0; j < PPW; ++j) {
        v2f a = (v2f){0.f, 0.f};
        #pragma unroll
        for (int d = 0; d < 9; ++d) {
            const float* p = &w1s[(d*NP + jbase + j) * 8];
            float4 ab = *(const float4*)p;
            v2f Cv = *(const v2f*)(p + 4);
            v2f Av = (v2f){ab.x, ab.y}, Bv = (v2f){ab.z, ab.w};
            a += crr[d]*Av + ccc[d]*Bv + cbb[d]*Cv;
        }
        z2[j] = a;
    }

    int dc = 0;
    v2f b0v = (v2f){0.f,0.f}, b1v = (v2f){0.f,0.f}, b2v = (v2f){0.f,0.f};
    float pfin[ND];

    // ---- solve loop: 1 barrier/iter; weight stream shared by both segments ----
    for (int it = 0; it < itMax; ++it) {
        // per-lane dc -> at most 2 distinct LDS addresses per wave (free 2-way broadcast)
        const float* w1r = &w1s[(dc*NP + jbase) * 8];
        const float* w2r = &w2s[jbase * 20];

        v2f acc2[ND];
        #pragma unroll
        for (int d = 0; d < ND; ++d) acc2[d] = (v2f){0.f, 0.f};

        #pragma unroll
        for (int j = 0; j < PPW; ++j) {
            const float* p = w1r + j*8;
            float4 ab = *(const float4*)p;
            v2f Cv = *(const v2f*)(p + 4);
            v2f Av = (v2f){ab.x, ab.y}, Bv = (v2f){ab.z, ab.w};
            v2f zv = z2[j];
            zv = b0v*Av + (b1v*Bv + (b2v*Cv + zv));
            z2[j] = zv;
            v2f hh;
            hh.x = fmaxf(zv.x, 0.f);
            hh.y = fmaxf(zv.y, 0.f);
            const float* qq = w2r + j*20;
            float4 w01 = *(const float4*)qq;
            float4 w23 = *(const float4*)(qq + 4);
            float4 w45 = *(const float4*)(qq + 8);
            float4 w67 = *(const float4*)(qq + 12);
            v2f w8 = *(const v2f*)(qq + 16);
            acc2[0] += hh * (v2f){w01.x, w01.y};
            acc2[1] += hh * (v2f){w01.z, w01.w};
            acc2[2] += hh * (v2f){w23.x, w23.y};
            acc2[3] += hh * (v2f){w23.z, w23.w};
            acc2[4] += hh * (v2f){w45.x, w45.y};
            acc2[5] += hh * (v2f){w45.z, w45.w};
            acc2[6] += hh * (v2f){w67.x, w67.y};
            acc2[7] += hh * (v2f){w67.z, w67.w};
            acc2[8] += hh * w8;
        }

        const int buf = it & 1;
        #pragma unroll
        for (int d = 0; d < ND; ++d)
            parts[buf][wv][d][lw] = acc2[d].x + acc2[d].y;
        __syncthreads();

        // combine in fixed wave order 0..3 -> bit-identical in all waves
        float acc[ND];
        #pragma unroll
        for (int d = 0; d < ND; ++d) acc[d] = parts[buf][0][d][lw];
        #pragma unroll
        for (int ow = 1; ow < 4; ++ow) {
            #pragma unroll
            for (int d = 0; d < ND; ++d) acc[d] += parts[buf][ow][d][lw];
        }

        // softmax + per-cell best digit (strict >: first max)
        float m9 = fmaxf(fmaxf(fmaxf(acc[0],acc[1]), fmaxf(acc[2],acc[3])),
                         fmaxf(fmaxf(acc[4],acc[5]), fmaxf(acc[6],acc[7])));
        m9 = fmaxf(m9, acc[8]);
        float s = 0.f;
        #pragma unroll
        for (int d = 0; d < ND; ++d) { acc[d] = __expf(acc[d] - m9); s += acc[d]; }
        float inv = 1.f / s;
        float bv = -1.f; int bd = 0;
        #pragma unroll
        for (int d = 0; d < ND; ++d) {
            acc[d] *= inv;
            if (acc[d] > bv) { bv = acc[d]; bd = d; }
        }

        // per-segment winner: butterfly within 32 lanes (+1 round if joined)
        float bvv = active ? bv : -1.f;
        float vmax = bvv;
        #pragma unroll
        for (int off = 16; off >= 1; off >>= 1)
            vmax = fmaxf(vmax, __shfl_xor(vmax, off));
        if (joined) vmax = fmaxf(vmax, __shfl_xor(vmax, 32));
        const unsigned long long segMask =
            joined ? ~0ull : (h ? 0xFFFFFFFF00000000ull : 0x00000000FFFFFFFFull);
        unsigned long long msk = __ballot(active && (bvv == vmax)) & segMask;
        const bool valid = (msk != 0);        // segment's board still solving
        int wl = valid ? (__ffsll(msk) - 1) : 0;  // lowest lane = lowest rank = lowest q
        int qw = __shfl(myq, wl);
        int dwn = __shfl(bd, wl);

        if (active && valid && myq == qw) {
            #pragma unroll
            for (int d = 0; d < ND; ++d) pfin[d] = acc[d];
            if (wv == 0) digit[idx][myq] = dwn;
            active = false;
        }
        const int pr = qw/9, pcc = qw%9, pb = (pr/3)*3 + pcc/3;
        b0v = (v2f)((valid && myr == pr)  ? 1.f : 0.f);
        b1v = (v2f)((valid && myc == pcc) ? 1.f : 0.f);
        b2v = (v2f)((valid && myb == pb)  ? 1.f : 0.f);
        if (valid) dc = dwn;
    }

    // ---- outputs ----
    __syncthreads();
    if (wv == 0 && myq < 81) {
        #pragma unroll
        for (int d = 0; d < ND; ++d) pom[myq*ND + d] = pfin[d];
    }
    {
        const int slot = (tid < 128) ? 0 : 1;
        const int t = (tid < 128) ? tid : tid - 128;
        const bool doSlot = (slot == 0) || !joined;
        const int bd2 = slot ? s1 : s0;
        float* fob = out + (size_t)nBoards * (CELLS * ND) + (size_t)bd2 * (CELLS * ND);
        if (doSlot) {
            for (int i = t; i < CELLS * ND; i += 128) {
                int q = i / ND, d = i - q * ND;
                fob[i] = (digit[slot][q] == d) ? 1.f : 0.f;
            }
        }
    }
}

extern "C" void kernel_launch(void* const* d_in, const int* in_sizes, int n_in,
                              void* d_out, int out_size, void* d_ws, size_t ws_size,
                              hipStream_t stream) {
    const float* x  = (const float*)d_in[0];
    // d_in[1] is the constraint mask c — structurally known, not needed.
    const float* W1 = (const float*)d_in[2];
    const float* W2 = (const float*)d_in[3];
    float* out = (float*)d_out;
    float* ws  = (float*)d_ws;
    int nBoards = in_sizes[0] / (CELLS * ND);
    int* neArr  = (int*)ws + NE_OFF;
    int* ordArr = (int*)ws + ORD_OFF;
    prep_kernel<<<1, 64, 0, stream>>>(W1, W2, ws);
    ne_kernel<<<nBoards, 64, 0, stream>>>(x, neArr, nBoards);
    part_kernel<<<1, 1024, 0, stream>>>(neArr, ordArr, nBoards);
    sudoku_kernel<<<nBoards, 256, 0, stream>>>(x, ws, ordArr, out, nBoards);
}